// Round 1
// baseline (326.815 us; speedup 1.0000x reference)
//
#include <hip/hip_runtime.h>
#include <stdint.h>

typedef __attribute__((ext_vector_type(4))) float f32x4;
typedef __attribute__((ext_vector_type(8))) short bf16x8;

#define SQKV 0.31947286f  /* 96^(-0.25) */

__device__ __forceinline__ unsigned short f2bf(float f) {
  union { float f; unsigned u; } v; v.f = f;
  unsigned r = v.u + 0x7FFFu + ((v.u >> 16) & 1u);
  return (unsigned short)(r >> 16);
}

// ---------------- convert fp32 -> bf16 (x4) ----------------
__global__ __launch_bounds__(256) void k_convert(const float* __restrict__ src,
                                                 unsigned short* __restrict__ dst,
                                                 int n4) {
  int i = blockIdx.x * 256 + threadIdx.x;
  if (i >= n4) return;
  float4 v = reinterpret_cast<const float4*>(src)[i];
  ushort4 o;
  o.x = f2bf(v.x); o.y = f2bf(v.y); o.z = f2bf(v.z); o.w = f2bf(v.w);
  reinterpret_cast<ushort4*>(dst)[i] = o;
}

// ---------------- x [b][c][n] f32 -> xT [b][n][c] bf16 ----------------
__global__ __launch_bounds__(256) void k_transpose(const float* __restrict__ x,
                                                   unsigned short* __restrict__ xT) {
  __shared__ float tile[32][33];
  const int t = threadIdx.x;
  const int j = t & 31, i0 = t >> 5;
  const int n0 = blockIdx.x * 32, c0 = blockIdx.y * 32, b = blockIdx.z;
  const float* src = x + ((size_t)b * 768 + c0) * 1024 + n0;
#pragma unroll
  for (int q = 0; q < 4; ++q)
    tile[i0 + q * 8][j] = src[(size_t)(i0 + q * 8) * 1024 + j];
  __syncthreads();
  unsigned short* dst = xT + ((size_t)b * 1024 + n0) * 768 + c0;
#pragma unroll
  for (int q = 0; q < 4; ++q)
    dst[(size_t)(i0 + q * 8) * 768 + j] = f2bf(tile[j][i0 + q * 8]);
}

// ---------------- QKV GEMM: C[o][n] = Wqkv[o][c] * xT[n][c]^T ----------------
// 128x128 tile, BK=32, 4 waves each 64x64 (4x4 frags of 16x16x32)
__global__ __launch_bounds__(256, 2) void k_gemm_qkv(
    const unsigned short* __restrict__ A,   // wqkv bf16 [2304][768]
    const unsigned short* __restrict__ Bx,  // xT bf16 [16][1024][768]
    const float* __restrict__ bias,         // [2304] f32
    unsigned short* __restrict__ qT,        // [16*8][1024][96]
    unsigned short* __restrict__ kT,        // [16*8][1024][96]
    unsigned short* __restrict__ vO) {      // [16*8][96][1024]
  __shared__ unsigned short As[128][40];
  __shared__ unsigned short Bs[128][40];
  const int t = threadIdx.x;
  const int b = blockIdx.y;
  const int tm = blockIdx.x >> 3, tn = blockIdx.x & 7;
  const int lane = t & 63, w = t >> 6, wr = w >> 1, wc = w & 1;

  const int ar0 = t >> 2, ac0 = (t & 3) << 3;
  const int ar1 = ar0 + 64;
  const unsigned short* aptr0 = A + (size_t)(tm * 128 + ar0) * 768 + ac0;
  const unsigned short* aptr1 = A + (size_t)(tm * 128 + ar1) * 768 + ac0;
  const unsigned short* bptr0 = Bx + (size_t)b * 1024 * 768 + (size_t)(tn * 128 + ar0) * 768 + ac0;
  const unsigned short* bptr1 = Bx + (size_t)b * 1024 * 768 + (size_t)(tn * 128 + ar1) * 768 + ac0;

  uint4 sa0 = *(const uint4*)aptr0;
  uint4 sa1 = *(const uint4*)aptr1;
  uint4 sb0 = *(const uint4*)bptr0;
  uint4 sb1 = *(const uint4*)bptr1;

  uint4* const wA0 = reinterpret_cast<uint4*>(&As[ar0][ac0]);
  uint4* const wA1 = reinterpret_cast<uint4*>(&As[ar1][ac0]);
  uint4* const wB0 = reinterpret_cast<uint4*>(&Bs[ar0][ac0]);
  uint4* const wB1 = reinterpret_cast<uint4*>(&Bs[ar1][ac0]);

  f32x4 acc[4][4];
#pragma unroll
  for (int mi = 0; mi < 4; ++mi)
#pragma unroll
    for (int ni = 0; ni < 4; ++ni) acc[mi][ni] = (f32x4)0.0f;

  const unsigned short* rA[4];
  const unsigned short* rB[4];
#pragma unroll
  for (int mi = 0; mi < 4; ++mi)
    rA[mi] = &As[wr * 64 + mi * 16 + (lane & 15)][(lane >> 4) << 3];
#pragma unroll
  for (int ni = 0; ni < 4; ++ni)
    rB[ni] = &Bs[wc * 64 + ni * 16 + (lane & 15)][(lane >> 4) << 3];

  for (int kt = 0; kt < 24; ++kt) {
    __syncthreads();
    *wA0 = sa0; *wA1 = sa1; *wB0 = sb0; *wB1 = sb1;
    __syncthreads();
    if (kt < 23) {
      aptr0 += 32; aptr1 += 32; bptr0 += 32; bptr1 += 32;
      sa0 = *(const uint4*)aptr0;
      sa1 = *(const uint4*)aptr1;
      sb0 = *(const uint4*)bptr0;
      sb1 = *(const uint4*)bptr1;
    }
    bf16x8 af[4], bfr[4];
#pragma unroll
    for (int mi = 0; mi < 4; ++mi) af[mi] = *reinterpret_cast<const bf16x8*>(rA[mi]);
#pragma unroll
    for (int ni = 0; ni < 4; ++ni) bfr[ni] = *reinterpret_cast<const bf16x8*>(rB[ni]);
#pragma unroll
    for (int mi = 0; mi < 4; ++mi)
#pragma unroll
      for (int ni = 0; ni < 4; ++ni)
        acc[mi][ni] = __builtin_amdgcn_mfma_f32_16x16x32_bf16(af[mi], bfr[ni], acc[mi][ni], 0, 0, 0);
  }

  // epilogue: bias, scale q/k, scatter to qT/kT ([bh][n][d]) and v ([bh][d][n])
#pragma unroll
  for (int mi = 0; mi < 4; ++mi) {
    const int o0 = tm * 128 + wr * 64 + mi * 16 + ((lane >> 4) << 2);
    const float4 bb = *reinterpret_cast<const float4*>(bias + o0);
    const float sc = (o0 < 1536) ? SQKV : 1.0f;
    const int om = o0 % 768;
    const int hh = om / 96;
    const int d0 = om % 96;
    const int region = o0 / 768;
    const size_t bh = (size_t)(b * 8 + hh);
#pragma unroll
    for (int ni = 0; ni < 4; ++ni) {
      const int nn = tn * 128 + wc * 64 + ni * 16 + (lane & 15);
      ushort4 st;
      st.x = f2bf((acc[mi][ni][0] + bb.x) * sc);
      st.y = f2bf((acc[mi][ni][1] + bb.y) * sc);
      st.z = f2bf((acc[mi][ni][2] + bb.z) * sc);
      st.w = f2bf((acc[mi][ni][3] + bb.w) * sc);
      if (region == 0) {
        *reinterpret_cast<ushort4*>(qT + (bh * 1024 + nn) * 96 + d0) = st;
      } else if (region == 1) {
        *reinterpret_cast<ushort4*>(kT + (bh * 1024 + nn) * 96 + d0) = st;
      } else {
        unsigned short* vp = vO + (bh * 96 + d0) * 1024 + nn;
        vp[0] = st.x; vp[1024] = st.y; vp[2048] = st.z; vp[3072] = st.w;
      }
    }
  }
}

// ---------------- flash attention ----------------
// grid.x = 2048: bid = nt*128 + bh  (XCD = bid%8 = bh%8 -> same-bh blocks share L2)
__global__ __launch_bounds__(256, 2) void k_attn(
    const unsigned short* __restrict__ qT,
    const unsigned short* __restrict__ kT,
    const unsigned short* __restrict__ vO,
    unsigned short* __restrict__ attoutT) {  // [16][1024][768]
  __shared__ unsigned short Qs[64][104];
  __shared__ unsigned short Ks[64][104];
  __shared__ unsigned short Vs[96][72];
  __shared__ unsigned short Ps[4][16][72];

  const int t = threadIdx.x, lane = t & 63, w = t >> 6;
  const int bid = blockIdx.x;
  const int bh = bid & 127, nt = bid >> 7;
  const int b = bh >> 3, hh = bh & 7;

  const unsigned short* qbase = qT + ((size_t)bh * 1024 + nt * 64) * 96;
  const unsigned short* kbase = kT + (size_t)bh * 1024 * 96;
  const unsigned short* vbase = vO + (size_t)bh * 96 * 1024;

  for (int c = t; c < 768; c += 256) {
    const int row = c / 12, c8 = c % 12;
    *reinterpret_cast<uint4*>(&Qs[row][c8 * 8]) =
        *reinterpret_cast<const uint4*>(qbase + (size_t)row * 96 + c8 * 8);
  }

  f32x4 oacc[6];
#pragma unroll
  for (int df = 0; df < 6; ++df) oacc[df] = (f32x4)0.0f;
  float run_m[4] = {-3.0e38f, -3.0e38f, -3.0e38f, -3.0e38f};
  float run_l[4] = {0.f, 0.f, 0.f, 0.f};

  for (int mt = 0; mt < 16; ++mt) {
    __syncthreads();  // prev compute done (covers Q-stage on first iter)
    const int m0 = mt * 64;
    for (int c = t; c < 768; c += 256) {
      const int row = c / 12, c8 = c % 12;
      *reinterpret_cast<uint4*>(&Ks[row][c8 * 8]) =
          *reinterpret_cast<const uint4*>(kbase + (size_t)(m0 + row) * 96 + c8 * 8);
    }
    for (int c = t; c < 768; c += 256) {
      const int d = c >> 3, c8 = c & 7;
      *reinterpret_cast<uint4*>(&Vs[d][c8 * 8]) =
          *reinterpret_cast<const uint4*>(vbase + (size_t)d * 1024 + m0 + c8 * 8);
    }
    __syncthreads();

    // QK^T: wave's 16 rows x 64 m
    f32x4 sf[4];
#pragma unroll
    for (int mf = 0; mf < 4; ++mf) sf[mf] = (f32x4)0.0f;
#pragma unroll
    for (int ks = 0; ks < 3; ++ks) {
      const bf16x8 af = *reinterpret_cast<const bf16x8*>(
          &Qs[w * 16 + (lane & 15)][ks * 32 + ((lane >> 4) << 3)]);
#pragma unroll
      for (int mf = 0; mf < 4; ++mf) {
        const bf16x8 bfr = *reinterpret_cast<const bf16x8*>(
            &Ks[mf * 16 + (lane & 15)][ks * 32 + ((lane >> 4) << 3)]);
        sf[mf] = __builtin_amdgcn_mfma_f32_16x16x32_bf16(af, bfr, sf[mf], 0, 0, 0);
      }
    }

    // online softmax, rows r: n_local = (lane>>4)*4 + r, m = mf*16 + (lane&15)
#pragma unroll
    for (int r = 0; r < 4; ++r) {
      float tmax = fmaxf(fmaxf(sf[0][r], sf[1][r]), fmaxf(sf[2][r], sf[3][r]));
      tmax = fmaxf(tmax, __shfl_xor(tmax, 1));
      tmax = fmaxf(tmax, __shfl_xor(tmax, 2));
      tmax = fmaxf(tmax, __shfl_xor(tmax, 4));
      tmax = fmaxf(tmax, __shfl_xor(tmax, 8));
      const float nm = fmaxf(run_m[r], tmax);
      const float alpha = __expf(run_m[r] - nm);
      const int prow = ((lane >> 4) << 2) + r;
      float ts = 0.f;
#pragma unroll
      for (int mf = 0; mf < 4; ++mf) {
        const float p = __expf(sf[mf][r] - nm);
        ts += p;
        Ps[w][prow][mf * 16 + (lane & 15)] = f2bf(p);
      }
      ts += __shfl_xor(ts, 1);
      ts += __shfl_xor(ts, 2);
      ts += __shfl_xor(ts, 4);
      ts += __shfl_xor(ts, 8);
      run_l[r] = run_l[r] * alpha + ts;
      run_m[r] = nm;
#pragma unroll
      for (int df = 0; df < 6; ++df) oacc[df][r] *= alpha;
    }

    // PV: oacc[n][d] += P[n][m] * V[d][m]^T
#pragma unroll
    for (int ms = 0; ms < 2; ++ms) {
      const bf16x8 pa = *reinterpret_cast<const bf16x8*>(
          &Ps[w][lane & 15][ms * 32 + ((lane >> 4) << 3)]);
#pragma unroll
      for (int df = 0; df < 6; ++df) {
        const bf16x8 vb = *reinterpret_cast<const bf16x8*>(
            &Vs[df * 16 + (lane & 15)][ms * 32 + ((lane >> 4) << 3)]);
        oacc[df] = __builtin_amdgcn_mfma_f32_16x16x32_bf16(pa, vb, oacc[df], 0, 0, 0);
      }
    }
  }

  // finalize: divide by row sums, bounce via LDS (Qs dead), coalesced store
#pragma unroll
  for (int r = 0; r < 4; ++r) {
    const float inv = 1.0f / run_l[r];
    const int row = w * 16 + ((lane >> 4) << 2) + r;
#pragma unroll
    for (int df = 0; df < 6; ++df)
      Qs[row][df * 16 + (lane & 15)] = f2bf(oacc[df][r] * inv);
  }
  __syncthreads();
  unsigned short* obase = attoutT + ((size_t)b * 1024 + nt * 64) * 768 + hh * 96;
  for (int c = t; c < 768; c += 256) {
    const int row = c / 12, c8 = c % 12;
    *reinterpret_cast<uint4*>(obase + (size_t)row * 768 + c8 * 8) =
        *reinterpret_cast<const uint4*>(&Qs[row][c8 * 8]);
  }
}

// ---------------- proj GEMM: C[n][o] = attoutT[n][c] * wproj[o][c]^T ----------------
__global__ __launch_bounds__(256, 2) void k_gemm_proj(
    const unsigned short* __restrict__ Aat,  // attoutT [16][1024][768]
    const unsigned short* __restrict__ Bw,   // wproj bf16 [768][768]
    const float* __restrict__ bias,          // [768]
    float* __restrict__ out) {               // [16][768][1024]
  __shared__ unsigned short As[128][40];
  __shared__ unsigned short Bs[128][40];
  const int t = threadIdx.x;
  const int b = blockIdx.y;
  const int tm = blockIdx.x / 6, tn = blockIdx.x % 6;
  const int lane = t & 63, w = t >> 6, wr = w >> 1, wc = w & 1;

  const int ar0 = t >> 2, ac0 = (t & 3) << 3;
  const int ar1 = ar0 + 64;
  const unsigned short* aptr0 = Aat + (size_t)b * 1024 * 768 + (size_t)(tm * 128 + ar0) * 768 + ac0;
  const unsigned short* aptr1 = Aat + (size_t)b * 1024 * 768 + (size_t)(tm * 128 + ar1) * 768 + ac0;
  const unsigned short* bptr0 = Bw + (size_t)(tn * 128 + ar0) * 768 + ac0;
  const unsigned short* bptr1 = Bw + (size_t)(tn * 128 + ar1) * 768 + ac0;

  uint4 sa0 = *(const uint4*)aptr0;
  uint4 sa1 = *(const uint4*)aptr1;
  uint4 sb0 = *(const uint4*)bptr0;
  uint4 sb1 = *(const uint4*)bptr1;

  uint4* const wA0 = reinterpret_cast<uint4*>(&As[ar0][ac0]);
  uint4* const wA1 = reinterpret_cast<uint4*>(&As[ar1][ac0]);
  uint4* const wB0 = reinterpret_cast<uint4*>(&Bs[ar0][ac0]);
  uint4* const wB1 = reinterpret_cast<uint4*>(&Bs[ar1][ac0]);

  f32x4 acc[4][4];
#pragma unroll
  for (int mi = 0; mi < 4; ++mi)
#pragma unroll
    for (int ni = 0; ni < 4; ++ni) acc[mi][ni] = (f32x4)0.0f;

  const unsigned short* rA[4];
  const unsigned short* rB[4];
#pragma unroll
  for (int mi = 0; mi < 4; ++mi)
    rA[mi] = &As[wr * 64 + mi * 16 + (lane & 15)][(lane >> 4) << 3];
#pragma unroll
  for (int ni = 0; ni < 4; ++ni)
    rB[ni] = &Bs[wc * 64 + ni * 16 + (lane & 15)][(lane >> 4) << 3];

  for (int kt = 0; kt < 24; ++kt) {
    __syncthreads();
    *wA0 = sa0; *wA1 = sa1; *wB0 = sb0; *wB1 = sb1;
    __syncthreads();
    if (kt < 23) {
      aptr0 += 32; aptr1 += 32; bptr0 += 32; bptr1 += 32;
      sa0 = *(const uint4*)aptr0;
      sa1 = *(const uint4*)aptr1;
      sb0 = *(const uint4*)bptr0;
      sb1 = *(const uint4*)bptr1;
    }
    bf16x8 af[4], bfr[4];
#pragma unroll
    for (int mi = 0; mi < 4; ++mi) af[mi] = *reinterpret_cast<const bf16x8*>(rA[mi]);
#pragma unroll
    for (int ni = 0; ni < 4; ++ni) bfr[ni] = *reinterpret_cast<const bf16x8*>(rB[ni]);
#pragma unroll
    for (int mi = 0; mi < 4; ++mi)
#pragma unroll
      for (int ni = 0; ni < 4; ++ni)
        acc[mi][ni] = __builtin_amdgcn_mfma_f32_16x16x32_bf16(af[mi], bfr[ni], acc[mi][ni], 0, 0, 0);
  }

  // epilogue: C[n][o] -> out[b][o][n], contiguous float4 along n
#pragma unroll
  for (int mi = 0; mi < 4; ++mi) {
    const int n0 = tm * 128 + wr * 64 + mi * 16 + ((lane >> 4) << 2);
#pragma unroll
    for (int ni = 0; ni < 4; ++ni) {
      const int o = tn * 128 + wc * 64 + ni * 16 + (lane & 15);
      const float bo = bias[o];
      float4 vv;
      vv.x = acc[mi][ni][0] + bo;
      vv.y = acc[mi][ni][1] + bo;
      vv.z = acc[mi][ni][2] + bo;
      vv.w = acc[mi][ni][3] + bo;
      *reinterpret_cast<float4*>(out + ((size_t)b * 768 + o) * 1024 + n0) = vv;
    }
  }
}

extern "C" void kernel_launch(void* const* d_in, const int* in_sizes, int n_in,
                              void* d_out, int out_size, void* d_ws, size_t ws_size,
                              hipStream_t stream) {
  const float* x = (const float*)d_in[0];
  const float* w_qkv = (const float*)d_in[1];
  const float* b_qkv = (const float*)d_in[2];
  const float* w_proj = (const float*)d_in[3];
  const float* b_proj = (const float*)d_in[4];
  float* out = (float*)d_out;

  unsigned short* ws = (unsigned short*)d_ws;
  unsigned short* wqkv_bf = ws;                          // 2304*768
  unsigned short* wproj_bf = wqkv_bf + 2304 * 768;       // 768*768
  unsigned short* xT = wproj_bf + 768 * 768;             // 16*1024*768 (reused as attoutT)
  unsigned short* qT = xT + (size_t)16 * 1024 * 768;     // 16*8*1024*96
  unsigned short* kT = qT + (size_t)16 * 8 * 1024 * 96;
  unsigned short* vO = kT + (size_t)16 * 8 * 1024 * 96;
  unsigned short* attoutT = xT;

  k_convert<<<(2304 * 768 / 4 + 255) / 256, 256, 0, stream>>>(w_qkv, wqkv_bf, 2304 * 768 / 4);
  k_convert<<<(768 * 768 / 4 + 255) / 256, 256, 0, stream>>>(w_proj, wproj_bf, 768 * 768 / 4);
  k_transpose<<<dim3(32, 24, 16), 256, 0, stream>>>(x, xT);
  k_gemm_qkv<<<dim3(144, 16), 256, 0, stream>>>(wqkv_bf, xT, b_qkv, qT, kT, vO);
  k_attn<<<2048, 256, 0, stream>>>(qT, kT, vO, attoutT);
  k_gemm_proj<<<dim3(48, 16), 256, 0, stream>>>(attoutT, wproj_bf, b_proj, out);
}

// Round 2
// 248.516 us; speedup vs baseline: 1.3151x; 1.3151x over previous
//
#include <hip/hip_runtime.h>
#include <stdint.h>

typedef __attribute__((ext_vector_type(4))) float f32x4;
typedef __attribute__((ext_vector_type(16))) float f32x16;
typedef __attribute__((ext_vector_type(8))) short bf16x8;

#define SQKV 0.38372606f  /* 96^(-0.25) * sqrt(log2(e)) -> logits in exp2 domain */

__device__ __forceinline__ unsigned short f2bf(float f) {
  union { float f; unsigned u; } v; v.f = f;
  unsigned r = v.u + 0x7FFFu + ((v.u >> 16) & 1u);
  return (unsigned short)(r >> 16);
}

__device__ __forceinline__ unsigned cvt_pk_bf16(float a, float b) {
  unsigned r;
  asm volatile("v_cvt_pk_bf16_f32 %0, %1, %2" : "=v"(r) : "v"(a), "v"(b));
  return r;
}
__device__ __forceinline__ void permswap(unsigned &a, unsigned &b) {
  asm volatile("v_permlane32_swap_b32 %0, %1" : "+v"(a), "+v"(b));
}

// ---------------- convert fp32 -> bf16 (x4) ----------------
__global__ __launch_bounds__(256) void k_convert(const float* __restrict__ src,
                                                 unsigned short* __restrict__ dst,
                                                 int n4) {
  int i = blockIdx.x * 256 + threadIdx.x;
  if (i >= n4) return;
  float4 v = reinterpret_cast<const float4*>(src)[i];
  ushort4 o;
  o.x = f2bf(v.x); o.y = f2bf(v.y); o.z = f2bf(v.z); o.w = f2bf(v.w);
  reinterpret_cast<ushort4*>(dst)[i] = o;
}

// ---------------- x [b][c][n] f32 -> xT [b][n][c] bf16 ----------------
__global__ __launch_bounds__(256) void k_transpose(const float* __restrict__ x,
                                                   unsigned short* __restrict__ xT) {
  __shared__ float tile[32][33];
  const int t = threadIdx.x;
  const int j = t & 31, i0 = t >> 5;
  const int n0 = blockIdx.x * 32, c0 = blockIdx.y * 32, b = blockIdx.z;
  const float* src = x + ((size_t)b * 768 + c0) * 1024 + n0;
#pragma unroll
  for (int q = 0; q < 4; ++q)
    tile[i0 + q * 8][j] = src[(size_t)(i0 + q * 8) * 1024 + j];
  __syncthreads();
  unsigned short* dst = xT + ((size_t)b * 1024 + n0) * 768 + c0;
#pragma unroll
  for (int q = 0; q < 4; ++q)
    dst[(size_t)(i0 + q * 8) * 768 + j] = f2bf(tile[j][i0 + q * 8]);
}

// ---------------- QKV GEMM: C[o][n] = Wqkv[o][c] * xT[n][c]^T ----------------
__global__ __launch_bounds__(256, 2) void k_gemm_qkv(
    const unsigned short* __restrict__ A,   // wqkv bf16 [2304][768]
    const unsigned short* __restrict__ Bx,  // xT bf16 [16][1024][768]
    const float* __restrict__ bias,         // [2304] f32
    unsigned short* __restrict__ qT,        // [16*8][1024][96]
    unsigned short* __restrict__ kT,        // [16*8][1024][96]
    unsigned short* __restrict__ vO) {      // [16*8][96][1024]
  __shared__ unsigned short As[128][40];
  __shared__ unsigned short Bs[128][40];
  const int t = threadIdx.x;
  const int b = blockIdx.y;
  const int tm = blockIdx.x >> 3, tn = blockIdx.x & 7;
  const int lane = t & 63, w = t >> 6, wr = w >> 1, wc = w & 1;

  const int ar0 = t >> 2, ac0 = (t & 3) << 3;
  const int ar1 = ar0 + 64;
  const unsigned short* aptr0 = A + (size_t)(tm * 128 + ar0) * 768 + ac0;
  const unsigned short* aptr1 = A + (size_t)(tm * 128 + ar1) * 768 + ac0;
  const unsigned short* bptr0 = Bx + (size_t)b * 1024 * 768 + (size_t)(tn * 128 + ar0) * 768 + ac0;
  const unsigned short* bptr1 = Bx + (size_t)b * 1024 * 768 + (size_t)(tn * 128 + ar1) * 768 + ac0;

  uint4 sa0 = *(const uint4*)aptr0;
  uint4 sa1 = *(const uint4*)aptr1;
  uint4 sb0 = *(const uint4*)bptr0;
  uint4 sb1 = *(const uint4*)bptr1;

  uint4* const wA0 = reinterpret_cast<uint4*>(&As[ar0][ac0]);
  uint4* const wA1 = reinterpret_cast<uint4*>(&As[ar1][ac0]);
  uint4* const wB0 = reinterpret_cast<uint4*>(&Bs[ar0][ac0]);
  uint4* const wB1 = reinterpret_cast<uint4*>(&Bs[ar1][ac0]);

  f32x4 acc[4][4];
#pragma unroll
  for (int mi = 0; mi < 4; ++mi)
#pragma unroll
    for (int ni = 0; ni < 4; ++ni) acc[mi][ni] = (f32x4)0.0f;

  const unsigned short* rA[4];
  const unsigned short* rB[4];
#pragma unroll
  for (int mi = 0; mi < 4; ++mi)
    rA[mi] = &As[wr * 64 + mi * 16 + (lane & 15)][(lane >> 4) << 3];
#pragma unroll
  for (int ni = 0; ni < 4; ++ni)
    rB[ni] = &Bs[wc * 64 + ni * 16 + (lane & 15)][(lane >> 4) << 3];

  for (int kt = 0; kt < 24; ++kt) {
    __syncthreads();
    *wA0 = sa0; *wA1 = sa1; *wB0 = sb0; *wB1 = sb1;
    __syncthreads();
    if (kt < 23) {
      aptr0 += 32; aptr1 += 32; bptr0 += 32; bptr1 += 32;
      sa0 = *(const uint4*)aptr0;
      sa1 = *(const uint4*)aptr1;
      sb0 = *(const uint4*)bptr0;
      sb1 = *(const uint4*)bptr1;
    }
    bf16x8 af[4], bfr[4];
#pragma unroll
    for (int mi = 0; mi < 4; ++mi) af[mi] = *reinterpret_cast<const bf16x8*>(rA[mi]);
#pragma unroll
    for (int ni = 0; ni < 4; ++ni) bfr[ni] = *reinterpret_cast<const bf16x8*>(rB[ni]);
#pragma unroll
    for (int mi = 0; mi < 4; ++mi)
#pragma unroll
      for (int ni = 0; ni < 4; ++ni)
        acc[mi][ni] = __builtin_amdgcn_mfma_f32_16x16x32_bf16(af[mi], bfr[ni], acc[mi][ni], 0, 0, 0);
  }

#pragma unroll
  for (int mi = 0; mi < 4; ++mi) {
    const int o0 = tm * 128 + wr * 64 + mi * 16 + ((lane >> 4) << 2);
    const float4 bb = *reinterpret_cast<const float4*>(bias + o0);
    const float sc = (o0 < 1536) ? SQKV : 1.0f;
    const int om = o0 % 768;
    const int hh = om / 96;
    const int d0 = om % 96;
    const int region = o0 / 768;
    const size_t bh = (size_t)(b * 8 + hh);
#pragma unroll
    for (int ni = 0; ni < 4; ++ni) {
      const int nn = tn * 128 + wc * 64 + ni * 16 + (lane & 15);
      ushort4 st;
      st.x = f2bf((acc[mi][ni][0] + bb.x) * sc);
      st.y = f2bf((acc[mi][ni][1] + bb.y) * sc);
      st.z = f2bf((acc[mi][ni][2] + bb.z) * sc);
      st.w = f2bf((acc[mi][ni][3] + bb.w) * sc);
      if (region == 0) {
        *reinterpret_cast<ushort4*>(qT + (bh * 1024 + nn) * 96 + d0) = st;
      } else if (region == 1) {
        *reinterpret_cast<ushort4*>(kT + (bh * 1024 + nn) * 96 + d0) = st;
      } else {
        unsigned short* vp = vO + (bh * 96 + d0) * 1024 + nn;
        vp[0] = st.x; vp[1024] = st.y; vp[2048] = st.z; vp[3072] = st.w;
      }
    }
  }
}

// ---------------- flash attention, 8-wave swapped-QK^T (32x32x16) ----------------
// grid 512: sw = (bid&7)*64 + bid>>3 ; bh = sw>>2, qt = sw&3
// wave: 32 q-rows (n = lane&31); lane-local P row; KVBLK=64.
__global__ __launch_bounds__(512, 2) void k_attn2(
    const unsigned short* __restrict__ qT,
    const unsigned short* __restrict__ kT,
    const unsigned short* __restrict__ vO,
    unsigned short* __restrict__ attoutT) {  // [16][1024][768]
  __shared__ unsigned short Ks[64][104];
  __shared__ unsigned short Vs[96][72];
  __shared__ float redbuf[8][32];

  const int t = threadIdx.x, lane = t & 63, wv = t >> 6;
  const int r31 = lane & 31, h = lane >> 5;
  const int sw = (blockIdx.x & 7) * 64 + (blockIdx.x >> 3);
  const int bh = sw >> 2, qt = sw & 3;
  const int b = bh >> 3, hh = bh & 7;
  const int n0 = qt * 256 + wv * 32;

  // Q fragments: Qf[ks] = Q[n0+r31][ks*16 + h*8 .. +8]  (B-operand layout)
  bf16x8 Qf[6];
  {
    const unsigned short* qrow = qT + ((size_t)bh * 1024 + n0 + r31) * 96 + h * 8;
#pragma unroll
    for (int ks = 0; ks < 6; ++ks)
      Qf[ks] = *reinterpret_cast<const bf16x8*>(qrow + ks * 16);
  }

  // staging: 1536 16B-chunks (K:768, V:768); thread owns chunks t, t+512, t+1024
  const unsigned short* gptr[3];
  unsigned short* lptr[3];
  int gstep[3];
#pragma unroll
  for (int i = 0; i < 3; ++i) {
    const int cc = t + i * 512;
    if (cc < 768) {
      const int row = cc / 12, col = (cc % 12) * 8;
      gptr[i] = kT + ((size_t)bh * 1024 + row) * 96 + col;
      lptr[i] = &Ks[row][col];
      gstep[i] = 64 * 96;
    } else {
      const int cv = cc - 768;
      const int d = cv >> 3, col = (cv & 7) * 8;
      gptr[i] = vO + ((size_t)bh * 96 + d) * 1024 + col;
      lptr[i] = &Vs[d][col];
      gstep[i] = 64;
    }
  }
  uint4 rg[3];
#pragma unroll
  for (int i = 0; i < 3; ++i) rg[i] = *reinterpret_cast<const uint4*>(gptr[i]);

  f32x16 oac[3];
#pragma unroll
  for (int dt = 0; dt < 3; ++dt) oac[dt] = (f32x16)0.0f;
  float run_m = -3.0e38f, run_l = 0.0f;

  for (int mt = 0; mt < 16; ++mt) {
    __syncthreads();  // all waves done reading Ks/Vs of previous tile
#pragma unroll
    for (int i = 0; i < 3; ++i) *reinterpret_cast<uint4*>(lptr[i]) = rg[i];
    if (mt < 15) {
#pragma unroll
      for (int i = 0; i < 3; ++i) {
        gptr[i] += gstep[i];
        rg[i] = *reinterpret_cast<const uint4*>(gptr[i]);  // hidden under compute
      }
    }
    __syncthreads();

    // QK^T swapped: D = K x Q^T -> lane holds S[n=r31][m], m-local (reg&3)+8*(reg>>2)+4h
    f32x16 sa = (f32x16)0.0f, sb = (f32x16)0.0f;
    __builtin_amdgcn_s_setprio(1);
#pragma unroll
    for (int ks = 0; ks < 6; ++ks) {
      const bf16x8 k0 = *reinterpret_cast<const bf16x8*>(&Ks[r31][ks * 16 + h * 8]);
      const bf16x8 k1 = *reinterpret_cast<const bf16x8*>(&Ks[32 + r31][ks * 16 + h * 8]);
      sa = __builtin_amdgcn_mfma_f32_32x32x16_bf16(k0, Qf[ks], sa, 0, 0, 0);
      sb = __builtin_amdgcn_mfma_f32_32x32x16_bf16(k1, Qf[ks], sb, 0, 0, 0);
    }
    __builtin_amdgcn_s_setprio(0);

    // row max over 64 m-values (32 in-reg + partner half)
    float m4a = fmaxf(sa[0], sa[1]), m4b = fmaxf(sa[2], sa[3]);
    float m4c = fmaxf(sb[0], sb[1]), m4d = fmaxf(sb[2], sb[3]);
#pragma unroll
    for (int i = 4; i < 16; i += 4) {
      m4a = fmaxf(m4a, fmaxf(sa[i], sa[i + 1]));
      m4b = fmaxf(m4b, fmaxf(sa[i + 2], sa[i + 3]));
      m4c = fmaxf(m4c, fmaxf(sb[i], sb[i + 1]));
      m4d = fmaxf(m4d, fmaxf(sb[i + 2], sb[i + 3]));
    }
    float tmax = fmaxf(fmaxf(m4a, m4b), fmaxf(m4c, m4d));
    tmax = fmaxf(tmax, __shfl_xor(tmax, 32));

    if (__any(tmax - run_m > 8.0f)) {  // defer-max (T13)
      const float nm = fmaxf(run_m, tmax);
      const float alpha = __builtin_amdgcn_exp2f(run_m - nm);
      run_m = nm;
      run_l *= alpha;
      if (lane < 32) redbuf[wv][lane] = alpha;  // per-wave, in-order LDS
      f32x4 a4[4];
#pragma unroll
      for (int q = 0; q < 4; ++q)
        a4[q] = *reinterpret_cast<const f32x4*>(&redbuf[wv][q * 8 + h * 4]);
#pragma unroll
      for (int dt = 0; dt < 3; ++dt)
#pragma unroll
        for (int q = 0; q < 4; ++q)
#pragma unroll
          for (int j = 0; j < 4; ++j)
            oac[dt][q * 4 + j] *= a4[q][j];
    }

    // P = exp2(S - m), row sum (4-way partials)
    float t0 = 0.f, t1 = 0.f, t2 = 0.f, t3 = 0.f;
#pragma unroll
    for (int i = 0; i < 16; i += 4) {
      sa[i]     = __builtin_amdgcn_exp2f(sa[i] - run_m);     t0 += sa[i];
      sa[i + 1] = __builtin_amdgcn_exp2f(sa[i + 1] - run_m); t1 += sa[i + 1];
      sa[i + 2] = __builtin_amdgcn_exp2f(sa[i + 2] - run_m); t2 += sa[i + 2];
      sa[i + 3] = __builtin_amdgcn_exp2f(sa[i + 3] - run_m); t3 += sa[i + 3];
    }
#pragma unroll
    for (int i = 0; i < 16; i += 4) {
      sb[i]     = __builtin_amdgcn_exp2f(sb[i] - run_m);     t0 += sb[i];
      sb[i + 1] = __builtin_amdgcn_exp2f(sb[i + 1] - run_m); t1 += sb[i + 1];
      sb[i + 2] = __builtin_amdgcn_exp2f(sb[i + 2] - run_m); t2 += sb[i + 2];
      sb[i + 3] = __builtin_amdgcn_exp2f(sb[i + 3] - run_m); t3 += sb[i + 3];
    }
    float ts = (t0 + t1) + (t2 + t3);
    ts += __shfl_xor(ts, 32);
    run_l += ts;

    // P -> bf16 A-frags (cvt_pk + permlane32_swap, T12), then PV
    union { bf16x8 v; unsigned u[4]; } pf;
    __builtin_amdgcn_s_setprio(1);
#pragma unroll
    for (int kst = 0; kst < 4; ++kst) {
      const f32x16& s = (kst < 2) ? sa : sb;
      const int base = (kst & 1) * 8;
      unsigned X = cvt_pk_bf16(s[base + 0], s[base + 1]);
      unsigned Y = cvt_pk_bf16(s[base + 2], s[base + 3]);
      unsigned Z = cvt_pk_bf16(s[base + 4], s[base + 5]);
      unsigned W = cvt_pk_bf16(s[base + 6], s[base + 7]);
      permswap(X, Z);
      permswap(Y, W);
      pf.u[0] = X; pf.u[1] = Y; pf.u[2] = Z; pf.u[3] = W;
#pragma unroll
      for (int dt = 0; dt < 3; ++dt) {
        const bf16x8 vf = *reinterpret_cast<const bf16x8*>(&Vs[dt * 32 + r31][kst * 16 + h * 8]);
        oac[dt] = __builtin_amdgcn_mfma_f32_32x32x16_bf16(pf.v, vf, oac[dt], 0, 0, 0);
      }
    }
    __builtin_amdgcn_s_setprio(0);
  }

  // finalize: broadcast 1/l into n'-layout, scale, store
  if (lane < 32) redbuf[wv][lane] = 1.0f / run_l;
  f32x4 i4[4];
#pragma unroll
  for (int q = 0; q < 4; ++q)
    i4[q] = *reinterpret_cast<const f32x4*>(&redbuf[wv][q * 8 + h * 4]);
  unsigned short* obase = attoutT + ((size_t)b * 1024 + n0) * 768 + hh * 96;
#pragma unroll
  for (int dt = 0; dt < 3; ++dt)
#pragma unroll
    for (int q = 0; q < 4; ++q)
#pragma unroll
      for (int j = 0; j < 4; ++j) {
        const int np = q * 8 + h * 4 + j;
        obase[(size_t)np * 768 + dt * 32 + r31] = f2bf(oac[dt][q * 4 + j] * i4[q][j]);
      }
}

// ---------------- proj GEMM: C[n][o] = attoutT[n][c] * wproj[o][c]^T ----------------
__global__ __launch_bounds__(256, 2) void k_gemm_proj(
    const unsigned short* __restrict__ Aat,  // attoutT [16][1024][768]
    const unsigned short* __restrict__ Bw,   // wproj bf16 [768][768]
    const float* __restrict__ bias,          // [768]
    float* __restrict__ out) {               // [16][768][1024]
  __shared__ unsigned short As[128][40];
  __shared__ unsigned short Bs[128][40];
  const int t = threadIdx.x;
  const int b = blockIdx.y;
  const int tm = blockIdx.x / 6, tn = blockIdx.x % 6;
  const int lane = t & 63, w = t >> 6, wr = w >> 1, wc = w & 1;

  const int ar0 = t >> 2, ac0 = (t & 3) << 3;
  const int ar1 = ar0 + 64;
  const unsigned short* aptr0 = Aat + (size_t)b * 1024 * 768 + (size_t)(tm * 128 + ar0) * 768 + ac0;
  const unsigned short* aptr1 = Aat + (size_t)b * 1024 * 768 + (size_t)(tm * 128 + ar1) * 768 + ac0;
  const unsigned short* bptr0 = Bw + (size_t)(tn * 128 + ar0) * 768 + ac0;
  const unsigned short* bptr1 = Bw + (size_t)(tn * 128 + ar1) * 768 + ac0;

  uint4 sa0 = *(const uint4*)aptr0;
  uint4 sa1 = *(const uint4*)aptr1;
  uint4 sb0 = *(const uint4*)bptr0;
  uint4 sb1 = *(const uint4*)bptr1;

  uint4* const wA0 = reinterpret_cast<uint4*>(&As[ar0][ac0]);
  uint4* const wA1 = reinterpret_cast<uint4*>(&As[ar1][ac0]);
  uint4* const wB0 = reinterpret_cast<uint4*>(&Bs[ar0][ac0]);
  uint4* const wB1 = reinterpret_cast<uint4*>(&Bs[ar1][ac0]);

  f32x4 acc[4][4];
#pragma unroll
  for (int mi = 0; mi < 4; ++mi)
#pragma unroll
    for (int ni = 0; ni < 4; ++ni) acc[mi][ni] = (f32x4)0.0f;

  const unsigned short* rA[4];
  const unsigned short* rB[4];
#pragma unroll
  for (int mi = 0; mi < 4; ++mi)
    rA[mi] = &As[wr * 64 + mi * 16 + (lane & 15)][(lane >> 4) << 3];
#pragma unroll
  for (int ni = 0; ni < 4; ++ni)
    rB[ni] = &Bs[wc * 64 + ni * 16 + (lane & 15)][(lane >> 4) << 3];

  for (int kt = 0; kt < 24; ++kt) {
    __syncthreads();
    *wA0 = sa0; *wA1 = sa1; *wB0 = sb0; *wB1 = sb1;
    __syncthreads();
    if (kt < 23) {
      aptr0 += 32; aptr1 += 32; bptr0 += 32; bptr1 += 32;
      sa0 = *(const uint4*)aptr0;
      sa1 = *(const uint4*)aptr1;
      sb0 = *(const uint4*)bptr0;
      sb1 = *(const uint4*)bptr1;
    }
    bf16x8 af[4], bfr[4];
#pragma unroll
    for (int mi = 0; mi < 4; ++mi) af[mi] = *reinterpret_cast<const bf16x8*>(rA[mi]);
#pragma unroll
    for (int ni = 0; ni < 4; ++ni) bfr[ni] = *reinterpret_cast<const bf16x8*>(rB[ni]);
#pragma unroll
    for (int mi = 0; mi < 4; ++mi)
#pragma unroll
      for (int ni = 0; ni < 4; ++ni)
        acc[mi][ni] = __builtin_amdgcn_mfma_f32_16x16x32_bf16(af[mi], bfr[ni], acc[mi][ni], 0, 0, 0);
  }

#pragma unroll
  for (int mi = 0; mi < 4; ++mi) {
    const int n0 = tm * 128 + wr * 64 + mi * 16 + ((lane >> 4) << 2);
#pragma unroll
    for (int ni = 0; ni < 4; ++ni) {
      const int o = tn * 128 + wc * 64 + ni * 16 + (lane & 15);
      const float bo = bias[o];
      float4 vv;
      vv.x = acc[mi][ni][0] + bo;
      vv.y = acc[mi][ni][1] + bo;
      vv.z = acc[mi][ni][2] + bo;
      vv.w = acc[mi][ni][3] + bo;
      *reinterpret_cast<float4*>(out + ((size_t)b * 768 + o) * 1024 + n0) = vv;
    }
  }
}

extern "C" void kernel_launch(void* const* d_in, const int* in_sizes, int n_in,
                              void* d_out, int out_size, void* d_ws, size_t ws_size,
                              hipStream_t stream) {
  const float* x = (const float*)d_in[0];
  const float* w_qkv = (const float*)d_in[1];
  const float* b_qkv = (const float*)d_in[2];
  const float* w_proj = (const float*)d_in[3];
  const float* b_proj = (const float*)d_in[4];
  float* out = (float*)d_out;

  unsigned short* ws = (unsigned short*)d_ws;
  unsigned short* wqkv_bf = ws;                          // 2304*768
  unsigned short* wproj_bf = wqkv_bf + 2304 * 768;       // 768*768
  unsigned short* xT = wproj_bf + 768 * 768;             // 16*1024*768 (reused as attoutT)
  unsigned short* qT = xT + (size_t)16 * 1024 * 768;     // 16*8*1024*96
  unsigned short* kT = qT + (size_t)16 * 8 * 1024 * 96;
  unsigned short* vO = kT + (size_t)16 * 8 * 1024 * 96;
  unsigned short* attoutT = xT;

  k_convert<<<(2304 * 768 / 4 + 255) / 256, 256, 0, stream>>>(w_qkv, wqkv_bf, 2304 * 768 / 4);
  k_convert<<<(768 * 768 / 4 + 255) / 256, 256, 0, stream>>>(w_proj, wproj_bf, 768 * 768 / 4);
  k_transpose<<<dim3(32, 24, 16), 256, 0, stream>>>(x, xT);
  k_gemm_qkv<<<dim3(144, 16), 256, 0, stream>>>(wqkv_bf, xT, b_qkv, qT, kT, vO);
  k_attn2<<<512, 512, 0, stream>>>(qT, kT, vO, attoutT);
  k_gemm_proj<<<dim3(48, 16), 256, 0, stream>>>(attoutT, wproj_bf, b_proj, out);
}

// Round 3
// 241.770 us; speedup vs baseline: 1.3518x; 1.0279x over previous
//
#include <hip/hip_runtime.h>
#include <stdint.h>

typedef __attribute__((ext_vector_type(4))) float f32x4;
typedef __attribute__((ext_vector_type(16))) float f32x16;
typedef __attribute__((ext_vector_type(8))) short bf16x8;

#define SQKV 0.38372606f  /* 96^(-0.25) * sqrt(log2(e)) -> logits in exp2 domain */

__device__ __forceinline__ unsigned short f2bf(float f) {
  union { float f; unsigned u; } v; v.f = f;
  unsigned r = v.u + 0x7FFFu + ((v.u >> 16) & 1u);
  return (unsigned short)(r >> 16);
}

__device__ __forceinline__ unsigned cvt_pk_bf16(float a, float b) {
  unsigned r;
  asm volatile("v_cvt_pk_bf16_f32 %0, %1, %2" : "=v"(r) : "v"(a), "v"(b));
  return r;
}
__device__ __forceinline__ void permswap(unsigned &a, unsigned &b) {
  asm volatile("v_permlane32_swap_b32 %0, %1" : "+v"(a), "+v"(b));
}

// ---------------- convert fp32 -> bf16 (x4) ----------------
__global__ __launch_bounds__(256) void k_convert(const float* __restrict__ src,
                                                 unsigned short* __restrict__ dst,
                                                 int n4) {
  int i = blockIdx.x * 256 + threadIdx.x;
  if (i >= n4) return;
  float4 v = reinterpret_cast<const float4*>(src)[i];
  ushort4 o;
  o.x = f2bf(v.x); o.y = f2bf(v.y); o.z = f2bf(v.z); o.w = f2bf(v.w);
  reinterpret_cast<ushort4*>(dst)[i] = o;
}

// ---------------- x [b][c][n] f32 -> xT [b][n][c] bf16 ----------------
__global__ __launch_bounds__(256) void k_transpose(const float* __restrict__ x,
                                                   unsigned short* __restrict__ xT) {
  __shared__ float tile[32][33];
  const int t = threadIdx.x;
  const int j = t & 31, i0 = t >> 5;
  const int n0 = blockIdx.x * 32, c0 = blockIdx.y * 32, b = blockIdx.z;
  const float* src = x + ((size_t)b * 768 + c0) * 1024 + n0;
#pragma unroll
  for (int q = 0; q < 4; ++q)
    tile[i0 + q * 8][j] = src[(size_t)(i0 + q * 8) * 1024 + j];
  __syncthreads();
  unsigned short* dst = xT + ((size_t)b * 1024 + n0) * 768 + c0;
#pragma unroll
  for (int q = 0; q < 4; ++q)
    dst[(size_t)(i0 + q * 8) * 768 + j] = f2bf(tile[j][i0 + q * 8]);
}

// ---------------- QKV GEMM: C[o][n] = Wqkv[o][c] * xT[n][c]^T ----------------
__global__ __launch_bounds__(256, 2) void k_gemm_qkv(
    const unsigned short* __restrict__ A,   // wqkv bf16 [2304][768]
    const unsigned short* __restrict__ Bx,  // xT bf16 [16][1024][768]
    const float* __restrict__ bias,         // [2304] f32
    unsigned short* __restrict__ qT,        // [16*8][1024][96]
    unsigned short* __restrict__ kT,        // [16*8][1024][96]
    unsigned short* __restrict__ vO) {      // [16*8][96][1024]
  __shared__ unsigned short As[128][40];
  __shared__ unsigned short Bs[128][40];
  const int t = threadIdx.x;
  const int b = blockIdx.y;
  const int tm = blockIdx.x >> 3, tn = blockIdx.x & 7;
  const int lane = t & 63, w = t >> 6, wr = w >> 1, wc = w & 1;

  const int ar0 = t >> 2, ac0 = (t & 3) << 3;
  const int ar1 = ar0 + 64;
  const unsigned short* aptr0 = A + (size_t)(tm * 128 + ar0) * 768 + ac0;
  const unsigned short* aptr1 = A + (size_t)(tm * 128 + ar1) * 768 + ac0;
  const unsigned short* bptr0 = Bx + (size_t)b * 1024 * 768 + (size_t)(tn * 128 + ar0) * 768 + ac0;
  const unsigned short* bptr1 = Bx + (size_t)b * 1024 * 768 + (size_t)(tn * 128 + ar1) * 768 + ac0;

  uint4 sa0 = *(const uint4*)aptr0;
  uint4 sa1 = *(const uint4*)aptr1;
  uint4 sb0 = *(const uint4*)bptr0;
  uint4 sb1 = *(const uint4*)bptr1;

  uint4* const wA0 = reinterpret_cast<uint4*>(&As[ar0][ac0]);
  uint4* const wA1 = reinterpret_cast<uint4*>(&As[ar1][ac0]);
  uint4* const wB0 = reinterpret_cast<uint4*>(&Bs[ar0][ac0]);
  uint4* const wB1 = reinterpret_cast<uint4*>(&Bs[ar1][ac0]);

  f32x4 acc[4][4];
#pragma unroll
  for (int mi = 0; mi < 4; ++mi)
#pragma unroll
    for (int ni = 0; ni < 4; ++ni) acc[mi][ni] = (f32x4)0.0f;

  const unsigned short* rA[4];
  const unsigned short* rB[4];
#pragma unroll
  for (int mi = 0; mi < 4; ++mi)
    rA[mi] = &As[wr * 64 + mi * 16 + (lane & 15)][(lane >> 4) << 3];
#pragma unroll
  for (int ni = 0; ni < 4; ++ni)
    rB[ni] = &Bs[wc * 64 + ni * 16 + (lane & 15)][(lane >> 4) << 3];

  for (int kt = 0; kt < 24; ++kt) {
    __syncthreads();
    *wA0 = sa0; *wA1 = sa1; *wB0 = sb0; *wB1 = sb1;
    __syncthreads();
    if (kt < 23) {
      aptr0 += 32; aptr1 += 32; bptr0 += 32; bptr1 += 32;
      sa0 = *(const uint4*)aptr0;
      sa1 = *(const uint4*)aptr1;
      sb0 = *(const uint4*)bptr0;
      sb1 = *(const uint4*)bptr1;
    }
    bf16x8 af[4], bfr[4];
#pragma unroll
    for (int mi = 0; mi < 4; ++mi) af[mi] = *reinterpret_cast<const bf16x8*>(rA[mi]);
#pragma unroll
    for (int ni = 0; ni < 4; ++ni) bfr[ni] = *reinterpret_cast<const bf16x8*>(rB[ni]);
#pragma unroll
    for (int mi = 0; mi < 4; ++mi)
#pragma unroll
      for (int ni = 0; ni < 4; ++ni)
        acc[mi][ni] = __builtin_amdgcn_mfma_f32_16x16x32_bf16(af[mi], bfr[ni], acc[mi][ni], 0, 0, 0);
  }

#pragma unroll
  for (int mi = 0; mi < 4; ++mi) {
    const int o0 = tm * 128 + wr * 64 + mi * 16 + ((lane >> 4) << 2);
    const float4 bb = *reinterpret_cast<const float4*>(bias + o0);
    const float sc = (o0 < 1536) ? SQKV : 1.0f;
    const int om = o0 % 768;
    const int hh = om / 96;
    const int d0 = om % 96;
    const int region = o0 / 768;
    const size_t bh = (size_t)(b * 8 + hh);
#pragma unroll
    for (int ni = 0; ni < 4; ++ni) {
      const int nn = tn * 128 + wc * 64 + ni * 16 + (lane & 15);
      ushort4 st;
      st.x = f2bf((acc[mi][ni][0] + bb.x) * sc);
      st.y = f2bf((acc[mi][ni][1] + bb.y) * sc);
      st.z = f2bf((acc[mi][ni][2] + bb.z) * sc);
      st.w = f2bf((acc[mi][ni][3] + bb.w) * sc);
      if (region == 0) {
        *reinterpret_cast<ushort4*>(qT + (bh * 1024 + nn) * 96 + d0) = st;
      } else if (region == 1) {
        *reinterpret_cast<ushort4*>(kT + (bh * 1024 + nn) * 96 + d0) = st;
      } else {
        unsigned short* vp = vO + (bh * 96 + d0) * 1024 + nn;
        vp[0] = st.x; vp[1024] = st.y; vp[2048] = st.z; vp[3072] = st.w;
      }
    }
  }
}

// ---------------- flash attention, 8-wave swapped-QK^T (32x32x16) ----------------
// grid 512: sw = (bid&7)*64 + bid>>3 ; bh = sw>>2, qt = sw&3
// Prefetch for tile t+1 is issued AFTER the second barrier (start of compute
// phase) so __syncthreads' implicit vmcnt(0) drain never waits on a
// just-issued load; the full compute phase covers the latency.
__global__ __launch_bounds__(512, 2) void k_attn2(
    const unsigned short* __restrict__ qT,
    const unsigned short* __restrict__ kT,
    const unsigned short* __restrict__ vO,
    unsigned short* __restrict__ attoutT) {  // [16][1024][768]
  __shared__ unsigned short Ks[64][104];
  __shared__ unsigned short Vs[96][72];
  __shared__ float redbuf[8][32];

  const int t = threadIdx.x, lane = t & 63, wv = t >> 6;
  const int r31 = lane & 31, h = lane >> 5;
  const int sw = (blockIdx.x & 7) * 64 + (blockIdx.x >> 3);
  const int bh = sw >> 2, qt = sw & 3;
  const int b = bh >> 3, hh = bh & 7;
  const int n0 = qt * 256 + wv * 32;

  // Q fragments: Qf[ks] = Q[n0+r31][ks*16 + h*8 .. +8]  (B-operand layout)
  bf16x8 Qf[6];
  {
    const unsigned short* qrow = qT + ((size_t)bh * 1024 + n0 + r31) * 96 + h * 8;
#pragma unroll
    for (int ks = 0; ks < 6; ++ks)
      Qf[ks] = *reinterpret_cast<const bf16x8*>(qrow + ks * 16);
  }

  // staging: 1536 16B-chunks (K:768, V:768); thread owns chunks t, t+512, t+1024
  const unsigned short* gptr[3];
  unsigned short* lptr[3];
  int gstep[3];
#pragma unroll
  for (int i = 0; i < 3; ++i) {
    const int cc = t + i * 512;
    if (cc < 768) {
      const int row = cc / 12, col = (cc % 12) * 8;
      gptr[i] = kT + ((size_t)bh * 1024 + row) * 96 + col;
      lptr[i] = &Ks[row][col];
      gstep[i] = 64 * 96;
    } else {
      const int cv = cc - 768;
      const int d = cv >> 3, col = (cv & 7) * 8;
      gptr[i] = vO + ((size_t)bh * 96 + d) * 1024 + col;
      lptr[i] = &Vs[d][col];
      gstep[i] = 64;
    }
  }
  uint4 rg[3];
#pragma unroll
  for (int i = 0; i < 3; ++i) rg[i] = *reinterpret_cast<const uint4*>(gptr[i]);

  f32x16 oac[3];
#pragma unroll
  for (int dt = 0; dt < 3; ++dt) oac[dt] = (f32x16)0.0f;
  float run_m = -3.0e38f, run_l = 0.0f;

  for (int mt = 0; mt < 16; ++mt) {
    __syncthreads();  // all waves done reading Ks/Vs of previous tile
#pragma unroll
    for (int i = 0; i < 3; ++i) *reinterpret_cast<uint4*>(lptr[i]) = rg[i];
    __syncthreads();
    if (mt < 15) {  // issue next-tile loads NOW: full compute phase hides them
#pragma unroll
      for (int i = 0; i < 3; ++i) {
        gptr[i] += gstep[i];
        rg[i] = *reinterpret_cast<const uint4*>(gptr[i]);
      }
    }

    // QK^T swapped: D = K x Q^T -> lane holds S[n=r31][m], m-local (reg&3)+8*(reg>>2)+4h
    f32x16 sa = (f32x16)0.0f, sb = (f32x16)0.0f;
    __builtin_amdgcn_s_setprio(1);
#pragma unroll
    for (int ks = 0; ks < 6; ++ks) {
      const bf16x8 k0 = *reinterpret_cast<const bf16x8*>(&Ks[r31][ks * 16 + h * 8]);
      const bf16x8 k1 = *reinterpret_cast<const bf16x8*>(&Ks[32 + r31][ks * 16 + h * 8]);
      sa = __builtin_amdgcn_mfma_f32_32x32x16_bf16(k0, Qf[ks], sa, 0, 0, 0);
      sb = __builtin_amdgcn_mfma_f32_32x32x16_bf16(k1, Qf[ks], sb, 0, 0, 0);
    }
    __builtin_amdgcn_s_setprio(0);

    // row max over 64 m-values (32 in-reg + partner half)
    float m4a = fmaxf(sa[0], sa[1]), m4b = fmaxf(sa[2], sa[3]);
    float m4c = fmaxf(sb[0], sb[1]), m4d = fmaxf(sb[2], sb[3]);
#pragma unroll
    for (int i = 4; i < 16; i += 4) {
      m4a = fmaxf(m4a, fmaxf(sa[i], sa[i + 1]));
      m4b = fmaxf(m4b, fmaxf(sa[i + 2], sa[i + 3]));
      m4c = fmaxf(m4c, fmaxf(sb[i], sb[i + 1]));
      m4d = fmaxf(m4d, fmaxf(sb[i + 2], sb[i + 3]));
    }
    float tmax = fmaxf(fmaxf(m4a, m4b), fmaxf(m4c, m4d));
    tmax = fmaxf(tmax, __shfl_xor(tmax, 32));

    if (__any(tmax - run_m > 8.0f)) {  // defer-max (T13)
      const float nm = fmaxf(run_m, tmax);
      const float alpha = __builtin_amdgcn_exp2f(run_m - nm);
      run_m = nm;
      run_l *= alpha;
      if (lane < 32) redbuf[wv][lane] = alpha;  // per-wave, in-order LDS
      f32x4 a4[4];
#pragma unroll
      for (int q = 0; q < 4; ++q)
        a4[q] = *reinterpret_cast<const f32x4*>(&redbuf[wv][q * 8 + h * 4]);
#pragma unroll
      for (int dt = 0; dt < 3; ++dt)
#pragma unroll
        for (int q = 0; q < 4; ++q)
#pragma unroll
          for (int j = 0; j < 4; ++j)
            oac[dt][q * 4 + j] *= a4[q][j];
    }

    // P = exp2(S - m), row sum (4-way partials)
    float t0 = 0.f, t1 = 0.f, t2 = 0.f, t3 = 0.f;
#pragma unroll
    for (int i = 0; i < 16; i += 4) {
      sa[i]     = __builtin_amdgcn_exp2f(sa[i] - run_m);     t0 += sa[i];
      sa[i + 1] = __builtin_amdgcn_exp2f(sa[i + 1] - run_m); t1 += sa[i + 1];
      sa[i + 2] = __builtin_amdgcn_exp2f(sa[i + 2] - run_m); t2 += sa[i + 2];
      sa[i + 3] = __builtin_amdgcn_exp2f(sa[i + 3] - run_m); t3 += sa[i + 3];
    }
#pragma unroll
    for (int i = 0; i < 16; i += 4) {
      sb[i]     = __builtin_amdgcn_exp2f(sb[i] - run_m);     t0 += sb[i];
      sb[i + 1] = __builtin_amdgcn_exp2f(sb[i + 1] - run_m); t1 += sb[i + 1];
      sb[i + 2] = __builtin_amdgcn_exp2f(sb[i + 2] - run_m); t2 += sb[i + 2];
      sb[i + 3] = __builtin_amdgcn_exp2f(sb[i + 3] - run_m); t3 += sb[i + 3];
    }
    float ts = (t0 + t1) + (t2 + t3);
    ts += __shfl_xor(ts, 32);
    run_l += ts;

    // P -> bf16 A-frags (cvt_pk + permlane32_swap, T12), then PV
    union { bf16x8 v; unsigned u[4]; } pf;
    __builtin_amdgcn_s_setprio(1);
#pragma unroll
    for (int kst = 0; kst < 4; ++kst) {
      const f32x16& s = (kst < 2) ? sa : sb;
      const int base = (kst & 1) * 8;
      unsigned X = cvt_pk_bf16(s[base + 0], s[base + 1]);
      unsigned Y = cvt_pk_bf16(s[base + 2], s[base + 3]);
      unsigned Z = cvt_pk_bf16(s[base + 4], s[base + 5]);
      unsigned W = cvt_pk_bf16(s[base + 6], s[base + 7]);
      permswap(X, Z);
      permswap(Y, W);
      pf.u[0] = X; pf.u[1] = Y; pf.u[2] = Z; pf.u[3] = W;
#pragma unroll
      for (int dt = 0; dt < 3; ++dt) {
        const bf16x8 vf = *reinterpret_cast<const bf16x8*>(&Vs[dt * 32 + r31][kst * 16 + h * 8]);
        oac[dt] = __builtin_amdgcn_mfma_f32_32x32x16_bf16(pf.v, vf, oac[dt], 0, 0, 0);
      }
    }
    __builtin_amdgcn_s_setprio(0);
  }

  // finalize: broadcast 1/l into n'-layout, scale, store
  if (lane < 32) redbuf[wv][lane] = 1.0f / run_l;
  f32x4 i4[4];
#pragma unroll
  for (int q = 0; q < 4; ++q)
    i4[q] = *reinterpret_cast<const f32x4*>(&redbuf[wv][q * 8 + h * 4]);
  unsigned short* obase = attoutT + ((size_t)b * 1024 + n0) * 768 + hh * 96;
#pragma unroll
  for (int dt = 0; dt < 3; ++dt)
#pragma unroll
    for (int q = 0; q < 4; ++q)
#pragma unroll
      for (int j = 0; j < 4; ++j) {
        const int np = q * 8 + h * 4 + j;
        obase[(size_t)np * 768 + dt * 32 + r31] = f2bf(oac[dt][q * 4 + j] * i4[q][j]);
      }
}

// ---------------- proj GEMM: C[n][o] = attoutT[n][c] * wproj[o][c]^T ----------------
__global__ __launch_bounds__(256, 2) void k_gemm_proj(
    const unsigned short* __restrict__ Aat,  // attoutT [16][1024][768]
    const unsigned short* __restrict__ Bw,   // wproj bf16 [768][768]
    const float* __restrict__ bias,          // [768]
    float* __restrict__ out) {               // [16][768][1024]
  __shared__ unsigned short As[128][40];
  __shared__ unsigned short Bs[128][40];
  const int t = threadIdx.x;
  const int b = blockIdx.y;
  const int tm = blockIdx.x / 6, tn = blockIdx.x % 6;
  const int lane = t & 63, w = t >> 6, wr = w >> 1, wc = w & 1;

  const int ar0 = t >> 2, ac0 = (t & 3) << 3;
  const int ar1 = ar0 + 64;
  const unsigned short* aptr0 = Aat + (size_t)b * 1024 * 768 + (size_t)(tm * 128 + ar0) * 768 + ac0;
  const unsigned short* aptr1 = Aat + (size_t)b * 1024 * 768 + (size_t)(tm * 128 + ar1) * 768 + ac0;
  const unsigned short* bptr0 = Bw + (size_t)(tn * 128 + ar0) * 768 + ac0;
  const unsigned short* bptr1 = Bw + (size_t)(tn * 128 + ar1) * 768 + ac0;

  uint4 sa0 = *(const uint4*)aptr0;
  uint4 sa1 = *(const uint4*)aptr1;
  uint4 sb0 = *(const uint4*)bptr0;
  uint4 sb1 = *(const uint4*)bptr1;

  uint4* const wA0 = reinterpret_cast<uint4*>(&As[ar0][ac0]);
  uint4* const wA1 = reinterpret_cast<uint4*>(&As[ar1][ac0]);
  uint4* const wB0 = reinterpret_cast<uint4*>(&Bs[ar0][ac0]);
  uint4* const wB1 = reinterpret_cast<uint4*>(&Bs[ar1][ac0]);

  f32x4 acc[4][4];
#pragma unroll
  for (int mi = 0; mi < 4; ++mi)
#pragma unroll
    for (int ni = 0; ni < 4; ++ni) acc[mi][ni] = (f32x4)0.0f;

  const unsigned short* rA[4];
  const unsigned short* rB[4];
#pragma unroll
  for (int mi = 0; mi < 4; ++mi)
    rA[mi] = &As[wr * 64 + mi * 16 + (lane & 15)][(lane >> 4) << 3];
#pragma unroll
  for (int ni = 0; ni < 4; ++ni)
    rB[ni] = &Bs[wc * 64 + ni * 16 + (lane & 15)][(lane >> 4) << 3];

  for (int kt = 0; kt < 24; ++kt) {
    __syncthreads();
    *wA0 = sa0; *wA1 = sa1; *wB0 = sb0; *wB1 = sb1;
    __syncthreads();
    if (kt < 23) {
      aptr0 += 32; aptr1 += 32; bptr0 += 32; bptr1 += 32;
      sa0 = *(const uint4*)aptr0;
      sa1 = *(const uint4*)aptr1;
      sb0 = *(const uint4*)bptr0;
      sb1 = *(const uint4*)bptr1;
    }
    bf16x8 af[4], bfr[4];
#pragma unroll
    for (int mi = 0; mi < 4; ++mi) af[mi] = *reinterpret_cast<const bf16x8*>(rA[mi]);
#pragma unroll
    for (int ni = 0; ni < 4; ++ni) bfr[ni] = *reinterpret_cast<const bf16x8*>(rB[ni]);
#pragma unroll
    for (int mi = 0; mi < 4; ++mi)
#pragma unroll
      for (int ni = 0; ni < 4; ++ni)
        acc[mi][ni] = __builtin_amdgcn_mfma_f32_16x16x32_bf16(af[mi], bfr[ni], acc[mi][ni], 0, 0, 0);
  }

#pragma unroll
  for (int mi = 0; mi < 4; ++mi) {
    const int n0 = tm * 128 + wr * 64 + mi * 16 + ((lane >> 4) << 2);
#pragma unroll
    for (int ni = 0; ni < 4; ++ni) {
      const int o = tn * 128 + wc * 64 + ni * 16 + (lane & 15);
      const float bo = bias[o];
      float4 vv;
      vv.x = acc[mi][ni][0] + bo;
      vv.y = acc[mi][ni][1] + bo;
      vv.z = acc[mi][ni][2] + bo;
      vv.w = acc[mi][ni][3] + bo;
      *reinterpret_cast<float4*>(out + ((size_t)b * 768 + o) * 1024 + n0) = vv;
    }
  }
}

extern "C" void kernel_launch(void* const* d_in, const int* in_sizes, int n_in,
                              void* d_out, int out_size, void* d_ws, size_t ws_size,
                              hipStream_t stream) {
  const float* x = (const float*)d_in[0];
  const float* w_qkv = (const float*)d_in[1];
  const float* b_qkv = (const float*)d_in[2];
  const float* w_proj = (const float*)d_in[3];
  const float* b_proj = (const float*)d_in[4];
  float* out = (float*)d_out;

  unsigned short* ws = (unsigned short*)d_ws;
  unsigned short* wqkv_bf = ws;                          // 2304*768
  unsigned short* wproj_bf = wqkv_bf + 2304 * 768;       // 768*768
  unsigned short* xT = wproj_bf + 768 * 768;             // 16*1024*768 (reused as attoutT)
  unsigned short* qT = xT + (size_t)16 * 1024 * 768;     // 16*8*1024*96
  unsigned short* kT = qT + (size_t)16 * 8 * 1024 * 96;
  unsigned short* vO = kT + (size_t)16 * 8 * 1024 * 96;
  unsigned short* attoutT = xT;

  k_convert<<<(2304 * 768 / 4 + 255) / 256, 256, 0, stream>>>(w_qkv, wqkv_bf, 2304 * 768 / 4);
  k_convert<<<(768 * 768 / 4 + 255) / 256, 256, 0, stream>>>(w_proj, wproj_bf, 768 * 768 / 4);
  k_transpose<<<dim3(32, 24, 16), 256, 0, stream>>>(x, xT);
  k_gemm_qkv<<<dim3(144, 16), 256, 0, stream>>>(wqkv_bf, xT, b_qkv, qT, kT, vO);
  k_attn2<<<512, 512, 0, stream>>>(qT, kT, vO, attoutT);
  k_gemm_proj<<<dim3(48, 16), 256, 0, stream>>>(attoutT, wproj_bf, b_proj, out);
}